// Round 10
// baseline (252.620 us; speedup 1.0000x reference)
//
#include <hip/hip_runtime.h>
#include <hip/hip_bf16.h>

typedef __bf16 b16v8 __attribute__((ext_vector_type(8)));
typedef __bf16 b16v4 __attribute__((ext_vector_type(4)));
typedef float  f32x4 __attribute__((ext_vector_type(4)));

#define BB 4
#define SS 2048
#define EE 1024
#define HH 16
#define DD 64

// 0.125 * log2(e): folds softmax scale + exp->exp2 conversion into q.
#define QSCALE 0.18033688011112042f
// Static softmax "max" in log2 domain.
#define CMAX 20.0f

__device__ __forceinline__ void async16(const __bf16* g, __bf16* l) {
  typedef __attribute__((address_space(1))) const unsigned int gu32;
  typedef __attribute__((address_space(3))) unsigned int lu32;
  __builtin_amdgcn_global_load_lds((gu32*)g, (lu32*)l, 16, 0, 0);
}

__device__ __forceinline__ f32x4 mfma16x16x16_bf16(b16v4 a, b16v4 b, f32x4 c) {
#if __has_builtin(__builtin_amdgcn_mfma_f32_16x16x16_bf16)
  return __builtin_amdgcn_mfma_f32_16x16x16_bf16(a, b, c, 0, 0, 0);
#else
  typedef short s16v4 __attribute__((ext_vector_type(4)));
  union U { b16v4 h; s16v4 s; };
  U ua, ub; ua.h = a; ub.h = b;
  return __builtin_amdgcn_mfma_f32_16x16x16bf16_1k(ua.s, ub.s, c, 0, 0, 0);
#endif
}

// ---------- merged prep: cast x + transpose both weights (one launch) ----------
__global__ __launch_bounds__(256) void prep_kernel(const float* __restrict__ x,
                                                   __bf16* __restrict__ xb,
                                                   const float* __restrict__ w_att,
                                                   __bf16* __restrict__ watt,
                                                   const float* __restrict__ w_proj,
                                                   __bf16* __restrict__ wproj) {
  __shared__ float t[32][33];
  const int bid = blockIdx.x;
  if (bid < 8192) {
    int i = bid * 256 + threadIdx.x;
    float4 f = ((const float4*)x)[i];
    b16v4 o = {(__bf16)f.x, (__bf16)f.y, (__bf16)f.z, (__bf16)f.w};
    ((b16v4*)xb)[i] = o;
    return;
  }
  const float* w;
  __bf16* wt;
  int N, local;
  if (bid < 11264) { w = w_att; wt = watt; N = 3072; local = bid - 8192; }
  else             { w = w_proj; wt = wproj; N = 1024; local = bid - 11264; }
  const int K = 1024;
  int n0 = (local % (N >> 5)) * 32, k0 = (local / (N >> 5)) * 32;
  int tx = threadIdx.x & 31, ty = threadIdx.x >> 5;  // 32x8
#pragma unroll
  for (int j = 0; j < 32; j += 8)
    t[ty + j][tx] = w[(size_t)(k0 + ty + j) * N + n0 + tx];
  __syncthreads();
#pragma unroll
  for (int j = 0; j < 32; j += 8)
    wt[(size_t)(n0 + ty + j) * K + k0 + tx] = (__bf16)t[tx][ty + j];
}

// ---------------- QKV GEMM: exact r7 kernel (best-measured, refcheck-passed) ----------------
__global__ __launch_bounds__(256) void gemm_qkv(const __bf16* __restrict__ A,
                                                const __bf16* __restrict__ Bt,
                                                __bf16* __restrict__ qb,
                                                __bf16* __restrict__ kb,
                                                __bf16* __restrict__ vtb,
                                                int K) {
  __shared__ __bf16 a_lds[3][128 * 32];
  __shared__ __bf16 b_lds[3][128 * 32];
  const int tid = threadIdx.x;
  const int lane = tid & 63;
  const int w = tid >> 6;
  const int wm = (w >> 1) * 64, wn = (w & 1) * 64;
  const int l16 = lane & 15, quad = lane >> 4;

  const int gx = gridDim.x;
  const int nwg = gx * gridDim.y;
  const int bid0 = blockIdx.y * gx + blockIdx.x;
  const int qq = nwg >> 3;
  const int xcd = bid0 & 7, idx = bid0 >> 3;
  const int wgid = xcd * qq + idx;
  const int bxx = wgid % gx, byy = wgid / gx;

  const __bf16* Ab = A + (size_t)byy * 128 * K;
  const __bf16* Bb = Bt + (size_t)bxx * 128 * K;

  auto stage = [&](int k0, int bufi) {
#pragma unroll
    for (int i = 0; i < 2; ++i) {
      int c = tid + i * 256;
      int row = c >> 2, ch = c & 3;
      async16(Ab + (size_t)row * K + k0 + ((ch ^ (row & 3)) * 8), a_lds[bufi] + c * 8);
    }
#pragma unroll
    for (int i = 0; i < 2; ++i) {
      int c = tid + i * 256;
      int row = c >> 2, ch = c & 3;
      async16(Bb + (size_t)row * K + k0 + ((ch ^ (row & 3)) * 8), b_lds[bufi] + c * 8);
    }
  };

  f32x4 acc[4][4];
#pragma unroll
  for (int i = 0; i < 4; ++i)
#pragma unroll
    for (int j = 0; j < 4; ++j) acc[i][j] = f32x4{0.f, 0.f, 0.f, 0.f};

  stage(0, 0);
  stage(32, 1);
  const int KT = K >> 5;
  const int sw = (quad ^ (l16 & 3)) * 8;
  int cur = 0;
  for (int kt = 0; kt < KT; ++kt) {
    if (kt + 1 < KT) asm volatile("s_waitcnt vmcnt(4)" ::: "memory");
    else             asm volatile("s_waitcnt vmcnt(0)" ::: "memory");
    __builtin_amdgcn_s_barrier();
    if (kt + 2 < KT) {
      int stb = cur + 2; if (stb > 2) stb -= 3;
      stage((kt + 2) << 5, stb);
    }
    const __bf16* ab = a_lds[cur];
    const __bf16* bb = b_lds[cur];
    b16v8 af[4], bf4[4];
#pragma unroll
    for (int t = 0; t < 4; ++t) {
      af[t] = *(const b16v8*)(ab + (wm + t * 16 + l16) * 32 + sw);
      bf4[t] = *(const b16v8*)(bb + (wn + t * 16 + l16) * 32 + sw);
    }
#pragma unroll
    for (int mt = 0; mt < 4; ++mt)
#pragma unroll
      for (int nt = 0; nt < 4; ++nt)
        acc[mt][nt] = __builtin_amdgcn_mfma_f32_16x16x32_bf16(af[mt], bf4[nt], acc[mt][nt], 0, 0, 0);
    cur = (cur == 2) ? 0 : cur + 1;
  }

#pragma unroll
  for (int mt = 0; mt < 4; ++mt)
#pragma unroll
    for (int nt = 0; nt < 4; ++nt) {
      int row = byy * 128 + wm + mt * 16 + quad * 4;
      int col = bxx * 128 + wn + nt * 16 + l16;
      int b = row >> 11, s = row & 2047;
      int sec = col >> 10, cc = col & 1023;
      int h = cc >> 6, d = cc & 63;
      if (sec == 2) {
        b16v4 vv = {(__bf16)acc[mt][nt][0], (__bf16)acc[mt][nt][1],
                    (__bf16)acc[mt][nt][2], (__bf16)acc[mt][nt][3]};
        *(b16v4*)(vtb + ((size_t)(b * HH + h) * DD + d) * SS + s) = vv;
      } else {
        __bf16* dst = (sec == 0) ? qb : kb;
        float sc = (sec == 0) ? QSCALE : 1.0f;
#pragma unroll
        for (int r = 0; r < 4; ++r)
          dst[(((size_t)(b * HH + h) * SS + s + r) << 6) + d] = (__bf16)(acc[mt][nt][r] * sc);
      }
    }
}

// ---------------- proj GEMM: exact r7 kernel ----------------
__global__ __launch_bounds__(256) void gemm_proj(const __bf16* __restrict__ A,
                                                 const __bf16* __restrict__ Bt,
                                                 float* __restrict__ out,
                                                 int N, int K) {
  __shared__ __bf16 a_lds[3][128 * 32];
  __shared__ __bf16 b_lds[3][64 * 32];
  const int tid = threadIdx.x;
  const int lane = tid & 63;
  const int w = tid >> 6;
  const int wm = (w >> 1) * 64, wn = (w & 1) * 32;
  const int l16 = lane & 15, quad = lane >> 4;

  const int gx = gridDim.x;
  const int nwg = gx * gridDim.y;
  const int bid0 = blockIdx.y * gx + blockIdx.x;
  const int qq = nwg >> 3;
  const int xcd = bid0 & 7, idx = bid0 >> 3;
  const int wgid = xcd * qq + idx;
  const int bxx = wgid % gx, byy = wgid / gx;

  const __bf16* Ab = A + (size_t)byy * 128 * K;
  const __bf16* Bb = Bt + (size_t)bxx * 64 * K;

  auto stage = [&](int k0, int bufi) {
#pragma unroll
    for (int i = 0; i < 2; ++i) {
      int c = tid + i * 256;
      int row = c >> 2, ch = c & 3;
      async16(Ab + (size_t)row * K + k0 + ((ch ^ (row & 3)) * 8), a_lds[bufi] + c * 8);
    }
    {
      int c = tid;
      int row = c >> 2, ch = c & 3;
      async16(Bb + (size_t)row * K + k0 + ((ch ^ (row & 3)) * 8), b_lds[bufi] + c * 8);
    }
  };

  f32x4 acc[4][2];
#pragma unroll
  for (int i = 0; i < 4; ++i)
#pragma unroll
    for (int j = 0; j < 2; ++j) acc[i][j] = f32x4{0.f, 0.f, 0.f, 0.f};

  stage(0, 0);
  stage(32, 1);
  const int KT = K >> 5;
  const int sw = (quad ^ (l16 & 3)) * 8;
  int cur = 0;
  for (int kt = 0; kt < KT; ++kt) {
    if (kt + 1 < KT) asm volatile("s_waitcnt vmcnt(3)" ::: "memory");
    else             asm volatile("s_waitcnt vmcnt(0)" ::: "memory");
    __builtin_amdgcn_s_barrier();
    if (kt + 2 < KT) {
      int stb = cur + 2; if (stb > 2) stb -= 3;
      stage((kt + 2) << 5, stb);
    }
    const __bf16* ab = a_lds[cur];
    const __bf16* bb = b_lds[cur];
    b16v8 af[4], bf4[2];
#pragma unroll
    for (int t = 0; t < 4; ++t)
      af[t] = *(const b16v8*)(ab + (wm + t * 16 + l16) * 32 + sw);
#pragma unroll
    for (int t = 0; t < 2; ++t)
      bf4[t] = *(const b16v8*)(bb + (wn + t * 16 + l16) * 32 + sw);
#pragma unroll
    for (int mt = 0; mt < 4; ++mt)
#pragma unroll
      for (int nt = 0; nt < 2; ++nt)
        acc[mt][nt] = __builtin_amdgcn_mfma_f32_16x16x32_bf16(af[mt], bf4[nt], acc[mt][nt], 0, 0, 0);
    cur = (cur == 2) ? 0 : cur + 1;
  }

#pragma unroll
  for (int mt = 0; mt < 4; ++mt)
#pragma unroll
    for (int nt = 0; nt < 2; ++nt)
#pragma unroll
      for (int r = 0; r < 4; ++r) {
        int row = byy * 128 + wm + mt * 16 + quad * 4 + r;
        int col = bxx * 64 + wn + nt * 16 + l16;
        out[(size_t)row * N + col] = acc[mt][nt][r];
      }
}

// ---------------- flash attention: r4-proven body + 3-buffer counted pipeline ----------------
// Compute body, softmax, reduction, output: byte-identical to the refcheck-passed
// kernel. ONLY the sync changed (same transformation that passed on both GEMMs in
// r7): __syncthreads (vmcnt(0) drain of stage(j) issued ~1 body ago) -> raw
// s_barrier + vmcnt(4) retiring stage(j) issued TWO bodies ago; vmcnt(0) only on
// the last iteration. stage(j+2) issued post-barrier targets the buffer whose
// readers finished at iter j-1 (mod-3 cycle) -> race-free. Ledger verified for
// qt=0 (prologue stages tile 0 only -> first iter is last, vmcnt(0)) and qt=1.
// LDS 48 KB -> 3 blocks/CU (was 4): same trade r7 made on the GEMMs.
__global__ __launch_bounds__(256, 4) void attn_kernel(const __bf16* __restrict__ qb,
                                                      const __bf16* __restrict__ kb,
                                                      const __bf16* __restrict__ vtb,
                                                      __bf16* __restrict__ y) {
  // [buf][ K tile 64x64 (4096) | V^T tile 64x64 (4096) ] x3 = 48 KB
  __shared__ __bf16 kv_lds[3][8192];
  const int tid = threadIdx.x;
  const int lane = tid & 63;
  const int w = tid >> 6;
  const int l16 = lane & 15, quad = lane >> 4;
  const int bh = blockIdx.x, p = blockIdx.y;
  const int b = bh >> 4, h = bh & 15;
  const __bf16* kbase = kb + (size_t)bh * SS * DD;
  const __bf16* vtbase = vtb + (size_t)bh * DD * SS;

  const int e = l16 & 7;
  const int koff0 = l16 * 64 + ((quad ^ e) * 8);
  const int koff1 = l16 * 64 + (((quad + 4) ^ e) * 8);
  int voff[4];
#pragma unroll
  for (int kf = 0; kf < 4; ++kf)
    voff[kf] = 4096 + l16 * 64 + (((kf * 2 + (quad >> 1)) ^ e) * 8) + ((quad & 1) * 4);

  int gK[2], gV[2], lK[2], lV[2];
#pragma unroll
  for (int i = 0; i < 2; ++i) {
    int L = tid + i * 256;
    int row = L >> 3, c = L & 7;
    gK[i] = row * DD + ((c ^ (row & 7)) * 8);
    lK[i] = L * 8;
    gV[i] = row * SS + ((c ^ (row & 7)) * 8);
    lV[i] = 4096 + L * 8;
  }
  auto stage = [&](int j, __bf16* buf) {
    const __bf16* kj = kbase + j * (64 * DD);
    const __bf16* vj = vtbase + j * 64;
#pragma unroll
    for (int i = 0; i < 2; ++i) async16(kj + gK[i], buf + lK[i]);
#pragma unroll
    for (int i = 0; i < 2; ++i) async16(vj + gV[i], buf + lV[i]);
  };

#pragma unroll
  for (int t = 0; t < 2; ++t) {
    const int qt = (t == 0) ? (31 - p) : p;

    b16v8 qf[2];
#pragma unroll
    for (int ks = 0; ks < 2; ++ks)
      qf[ks] = *(const b16v8*)(qb + ((size_t)bh * SS + qt * 64 + w * 16 + l16) * DD + ks * 32 + quad * 8);

    f32x4 o[4];
#pragma unroll
    for (int dt = 0; dt < 4; ++dt) o[dt] = f32x4{0.f, 0.f, 0.f, 0.f};
    f32x4 lv = {0.f, 0.f, 0.f, 0.f};

    __syncthreads();            // prior pass readers done; vmcnt clean (last iter drained)
    stage(0, kv_lds[0]);        // prologue: tiles 0 (and 1 if present)
    if (qt >= 1) stage(1, kv_lds[1]);

    int cur = 0;
    for (int j = 0; j <= qt; ++j) {
      // counted wait: retire stage(j) (issued 2 bodies ago); keep stage(j+1) in flight
      if (j < qt) asm volatile("s_waitcnt vmcnt(4)" ::: "memory");
      else        asm volatile("s_waitcnt vmcnt(0)" ::: "memory");
      __builtin_amdgcn_s_barrier();  // raw: no implicit drain
      if (j + 2 <= qt) {
        int nb = cur + 2; if (nb > 2) nb -= 3;
        stage(j + 2, kv_lds[nb]);
      }
      const __bf16* buf = kv_lds[cur];

      f32x4 s[4];
#pragma unroll
      for (int kf = 0; kf < 4; ++kf) s[kf] = f32x4{-CMAX, -CMAX, -CMAX, -CMAX};
      __builtin_amdgcn_s_setprio(1);
#pragma unroll
      for (int kf = 0; kf < 4; ++kf) {
        b16v8 k0 = *(const b16v8*)(buf + koff0 + kf * 1024);
        b16v8 k1 = *(const b16v8*)(buf + koff1 + kf * 1024);
        s[kf] = __builtin_amdgcn_mfma_f32_16x16x32_bf16(k0, qf[0], s[kf], 0, 0, 0);
        s[kf] = __builtin_amdgcn_mfma_f32_16x16x32_bf16(k1, qf[1], s[kf], 0, 0, 0);
      }
      __builtin_amdgcn_s_setprio(0);
      if (j == qt) {
        int ql = w * 16 + l16;
#pragma unroll
        for (int kf = 0; kf < 4; ++kf)
#pragma unroll
          for (int r = 0; r < 4; ++r)
            if (kf * 16 + quad * 4 + r > ql) s[kf][r] = -1e30f;
      }
#pragma unroll
      for (int kf = 0; kf < 4; ++kf)
#pragma unroll
        for (int r = 0; r < 4; ++r) s[kf][r] = __builtin_amdgcn_exp2f(s[kf][r]);
      lv += (s[0] + s[1]) + (s[2] + s[3]);
      __builtin_amdgcn_s_setprio(1);
#pragma unroll
      for (int kf = 0; kf < 4; ++kf) {
        b16v4 pf = {(__bf16)s[kf][0], (__bf16)s[kf][1], (__bf16)s[kf][2], (__bf16)s[kf][3]};
#pragma unroll
        for (int dt = 0; dt < 4; ++dt) {
          b16v4 vf = *(const b16v4*)(buf + voff[kf] + dt * 1024);
          o[dt] = mfma16x16x16_bf16(vf, pf, o[dt]);
        }
      }
      __builtin_amdgcn_s_setprio(0);
      cur = (cur == 2) ? 0 : cur + 1;
    }

    float lr = (lv[0] + lv[1]) + (lv[2] + lv[3]);
    lr += __shfl_xor(lr, 16);
    lr += __shfl_xor(lr, 32);
    float inv = 1.0f / lr;
    int q = qt * 64 + w * 16 + l16;
#pragma unroll
    for (int dt = 0; dt < 4; ++dt) {
      b16v4 ov = {(__bf16)(o[dt][0] * inv), (__bf16)(o[dt][1] * inv),
                  (__bf16)(o[dt][2] * inv), (__bf16)(o[dt][3] * inv)};
      *(b16v4*)(y + ((size_t)b * SS + q) * EE + h * 64 + dt * 16 + quad * 4) = ov;
    }
  }
}

extern "C" void kernel_launch(void* const* d_in, const int* in_sizes, int n_in,
                              void* d_out, int out_size, void* d_ws, size_t ws_size,
                              hipStream_t stream) {
  (void)in_sizes; (void)n_in; (void)out_size; (void)ws_size;
  const float* x = (const float*)d_in[0];
  const float* w_att = (const float*)d_in[1];
  const float* w_proj = (const float*)d_in[2];
  float* out = (float*)d_out;

  char* ws = (char*)d_ws;
  size_t off = 0;
  auto alloc = [&](size_t elems) { __bf16* p = (__bf16*)(ws + off); off += elems * 2; return p; };
  __bf16* xb = alloc(8388608);     // x bf16; reused as y after attention
  __bf16* qb = alloc(8388608);     // [BH][S][D] (pre-scaled by 0.125*log2e)
  __bf16* kb = alloc(8388608);     // [BH][S][D]
  __bf16* vtb = alloc(8388608);    // [BH][D][S] (written transposed by gemm_qkv)
  __bf16* watt = alloc(3145728);   // w_att^T  [3072][1024]
  __bf16* wproj = alloc(1048576);  // w_proj^T [1024][1024]

  prep_kernel<<<12288, 256, 0, stream>>>(x, xb, w_att, watt, w_proj, wproj);
  gemm_qkv<<<dim3(24, 64), 256, 0, stream>>>(xb, watt, qb, kb, vtb, 1024);
  attn_kernel<<<dim3(64, 16), 256, 0, stream>>>(qb, kb, vtb, xb);
  gemm_proj<<<dim3(16, 64), 256, 0, stream>>>(xb, wproj, out, 1024, 1024);
}

// Round 11
// 239.897 us; speedup vs baseline: 1.0530x; 1.0530x over previous
//
#include <hip/hip_runtime.h>
#include <hip/hip_bf16.h>

typedef __bf16 b16v8 __attribute__((ext_vector_type(8)));
typedef __bf16 b16v4 __attribute__((ext_vector_type(4)));
typedef float  f32x4 __attribute__((ext_vector_type(4)));

#define BB 4
#define SS 2048
#define EE 1024
#define HH 16
#define DD 64

// 0.125 * log2(e): folds softmax scale + exp->exp2 conversion into q.
#define QSCALE 0.18033688011112042f
// Static softmax "max" in log2 domain.
#define CMAX 20.0f

__device__ __forceinline__ void async16(const __bf16* g, __bf16* l) {
  typedef __attribute__((address_space(1))) const unsigned int gu32;
  typedef __attribute__((address_space(3))) unsigned int lu32;
  __builtin_amdgcn_global_load_lds((gu32*)g, (lu32*)l, 16, 0, 0);
}

__device__ __forceinline__ f32x4 mfma16x16x16_bf16(b16v4 a, b16v4 b, f32x4 c) {
#if __has_builtin(__builtin_amdgcn_mfma_f32_16x16x16_bf16)
  return __builtin_amdgcn_mfma_f32_16x16x16_bf16(a, b, c, 0, 0, 0);
#else
  typedef short s16v4 __attribute__((ext_vector_type(4)));
  union U { b16v4 h; s16v4 s; };
  U ua, ub; ua.h = a; ub.h = b;
  return __builtin_amdgcn_mfma_f32_16x16x16bf16_1k(ua.s, ub.s, c, 0, 0, 0);
#endif
}

// ---------- merged prep: cast x + transpose both weights (one launch) ----------
__global__ __launch_bounds__(256) void prep_kernel(const float* __restrict__ x,
                                                   __bf16* __restrict__ xb,
                                                   const float* __restrict__ w_att,
                                                   __bf16* __restrict__ watt,
                                                   const float* __restrict__ w_proj,
                                                   __bf16* __restrict__ wproj) {
  __shared__ float t[32][33];
  const int bid = blockIdx.x;
  if (bid < 8192) {
    int i = bid * 256 + threadIdx.x;
    float4 f = ((const float4*)x)[i];
    b16v4 o = {(__bf16)f.x, (__bf16)f.y, (__bf16)f.z, (__bf16)f.w};
    ((b16v4*)xb)[i] = o;
    return;
  }
  const float* w;
  __bf16* wt;
  int N, local;
  if (bid < 11264) { w = w_att; wt = watt; N = 3072; local = bid - 8192; }
  else             { w = w_proj; wt = wproj; N = 1024; local = bid - 11264; }
  const int K = 1024;
  int n0 = (local % (N >> 5)) * 32, k0 = (local / (N >> 5)) * 32;
  int tx = threadIdx.x & 31, ty = threadIdx.x >> 5;  // 32x8
#pragma unroll
  for (int j = 0; j < 32; j += 8)
    t[ty + j][tx] = w[(size_t)(k0 + ty + j) * N + n0 + tx];
  __syncthreads();
#pragma unroll
  for (int j = 0; j < 32; j += 8)
    wt[(size_t)(n0 + ty + j) * K + k0 + tx] = (__bf16)t[tx][ty + j];
}

// ---------------- QKV GEMM: exact r7 kernel (best-measured, refcheck-passed) ----------------
__global__ __launch_bounds__(256) void gemm_qkv(const __bf16* __restrict__ A,
                                                const __bf16* __restrict__ Bt,
                                                __bf16* __restrict__ qb,
                                                __bf16* __restrict__ kb,
                                                __bf16* __restrict__ vtb,
                                                int K) {
  __shared__ __bf16 a_lds[3][128 * 32];
  __shared__ __bf16 b_lds[3][128 * 32];
  const int tid = threadIdx.x;
  const int lane = tid & 63;
  const int w = tid >> 6;
  const int wm = (w >> 1) * 64, wn = (w & 1) * 64;
  const int l16 = lane & 15, quad = lane >> 4;

  const int gx = gridDim.x;
  const int nwg = gx * gridDim.y;
  const int bid0 = blockIdx.y * gx + blockIdx.x;
  const int qq = nwg >> 3;
  const int xcd = bid0 & 7, idx = bid0 >> 3;
  const int wgid = xcd * qq + idx;
  const int bxx = wgid % gx, byy = wgid / gx;

  const __bf16* Ab = A + (size_t)byy * 128 * K;
  const __bf16* Bb = Bt + (size_t)bxx * 128 * K;

  auto stage = [&](int k0, int bufi) {
#pragma unroll
    for (int i = 0; i < 2; ++i) {
      int c = tid + i * 256;
      int row = c >> 2, ch = c & 3;
      async16(Ab + (size_t)row * K + k0 + ((ch ^ (row & 3)) * 8), a_lds[bufi] + c * 8);
    }
#pragma unroll
    for (int i = 0; i < 2; ++i) {
      int c = tid + i * 256;
      int row = c >> 2, ch = c & 3;
      async16(Bb + (size_t)row * K + k0 + ((ch ^ (row & 3)) * 8), b_lds[bufi] + c * 8);
    }
  };

  f32x4 acc[4][4];
#pragma unroll
  for (int i = 0; i < 4; ++i)
#pragma unroll
    for (int j = 0; j < 4; ++j) acc[i][j] = f32x4{0.f, 0.f, 0.f, 0.f};

  stage(0, 0);
  stage(32, 1);
  const int KT = K >> 5;
  const int sw = (quad ^ (l16 & 3)) * 8;
  int cur = 0;
  for (int kt = 0; kt < KT; ++kt) {
    if (kt + 1 < KT) asm volatile("s_waitcnt vmcnt(4)" ::: "memory");
    else             asm volatile("s_waitcnt vmcnt(0)" ::: "memory");
    __builtin_amdgcn_s_barrier();
    if (kt + 2 < KT) {
      int stb = cur + 2; if (stb > 2) stb -= 3;
      stage((kt + 2) << 5, stb);
    }
    const __bf16* ab = a_lds[cur];
    const __bf16* bb = b_lds[cur];
    b16v8 af[4], bf4[4];
#pragma unroll
    for (int t = 0; t < 4; ++t) {
      af[t] = *(const b16v8*)(ab + (wm + t * 16 + l16) * 32 + sw);
      bf4[t] = *(const b16v8*)(bb + (wn + t * 16 + l16) * 32 + sw);
    }
#pragma unroll
    for (int mt = 0; mt < 4; ++mt)
#pragma unroll
      for (int nt = 0; nt < 4; ++nt)
        acc[mt][nt] = __builtin_amdgcn_mfma_f32_16x16x32_bf16(af[mt], bf4[nt], acc[mt][nt], 0, 0, 0);
    cur = (cur == 2) ? 0 : cur + 1;
  }

#pragma unroll
  for (int mt = 0; mt < 4; ++mt)
#pragma unroll
    for (int nt = 0; nt < 4; ++nt) {
      int row = byy * 128 + wm + mt * 16 + quad * 4;
      int col = bxx * 128 + wn + nt * 16 + l16;
      int b = row >> 11, s = row & 2047;
      int sec = col >> 10, cc = col & 1023;
      int h = cc >> 6, d = cc & 63;
      if (sec == 2) {
        b16v4 vv = {(__bf16)acc[mt][nt][0], (__bf16)acc[mt][nt][1],
                    (__bf16)acc[mt][nt][2], (__bf16)acc[mt][nt][3]};
        *(b16v4*)(vtb + ((size_t)(b * HH + h) * DD + d) * SS + s) = vv;
      } else {
        __bf16* dst = (sec == 0) ? qb : kb;
        float sc = (sec == 0) ? QSCALE : 1.0f;
#pragma unroll
        for (int r = 0; r < 4; ++r)
          dst[(((size_t)(b * HH + h) * SS + s + r) << 6) + d] = (__bf16)(acc[mt][nt][r] * sc);
      }
    }
}

// ---------------- proj GEMM: exact r7 kernel ----------------
__global__ __launch_bounds__(256) void gemm_proj(const __bf16* __restrict__ A,
                                                 const __bf16* __restrict__ Bt,
                                                 float* __restrict__ out,
                                                 int N, int K) {
  __shared__ __bf16 a_lds[3][128 * 32];
  __shared__ __bf16 b_lds[3][64 * 32];
  const int tid = threadIdx.x;
  const int lane = tid & 63;
  const int w = tid >> 6;
  const int wm = (w >> 1) * 64, wn = (w & 1) * 32;
  const int l16 = lane & 15, quad = lane >> 4;

  const int gx = gridDim.x;
  const int nwg = gx * gridDim.y;
  const int bid0 = blockIdx.y * gx + blockIdx.x;
  const int qq = nwg >> 3;
  const int xcd = bid0 & 7, idx = bid0 >> 3;
  const int wgid = xcd * qq + idx;
  const int bxx = wgid % gx, byy = wgid / gx;

  const __bf16* Ab = A + (size_t)byy * 128 * K;
  const __bf16* Bb = Bt + (size_t)bxx * 64 * K;

  auto stage = [&](int k0, int bufi) {
#pragma unroll
    for (int i = 0; i < 2; ++i) {
      int c = tid + i * 256;
      int row = c >> 2, ch = c & 3;
      async16(Ab + (size_t)row * K + k0 + ((ch ^ (row & 3)) * 8), a_lds[bufi] + c * 8);
    }
    {
      int c = tid;
      int row = c >> 2, ch = c & 3;
      async16(Bb + (size_t)row * K + k0 + ((ch ^ (row & 3)) * 8), b_lds[bufi] + c * 8);
    }
  };

  f32x4 acc[4][2];
#pragma unroll
  for (int i = 0; i < 4; ++i)
#pragma unroll
    for (int j = 0; j < 2; ++j) acc[i][j] = f32x4{0.f, 0.f, 0.f, 0.f};

  stage(0, 0);
  stage(32, 1);
  const int KT = K >> 5;
  const int sw = (quad ^ (l16 & 3)) * 8;
  int cur = 0;
  for (int kt = 0; kt < KT; ++kt) {
    if (kt + 1 < KT) asm volatile("s_waitcnt vmcnt(3)" ::: "memory");
    else             asm volatile("s_waitcnt vmcnt(0)" ::: "memory");
    __builtin_amdgcn_s_barrier();
    if (kt + 2 < KT) {
      int stb = cur + 2; if (stb > 2) stb -= 3;
      stage((kt + 2) << 5, stb);
    }
    const __bf16* ab = a_lds[cur];
    const __bf16* bb = b_lds[cur];
    b16v8 af[4], bf4[2];
#pragma unroll
    for (int t = 0; t < 4; ++t)
      af[t] = *(const b16v8*)(ab + (wm + t * 16 + l16) * 32 + sw);
#pragma unroll
    for (int t = 0; t < 2; ++t)
      bf4[t] = *(const b16v8*)(bb + (wn + t * 16 + l16) * 32 + sw);
#pragma unroll
    for (int mt = 0; mt < 4; ++mt)
#pragma unroll
      for (int nt = 0; nt < 2; ++nt)
        acc[mt][nt] = __builtin_amdgcn_mfma_f32_16x16x32_bf16(af[mt], bf4[nt], acc[mt][nt], 0, 0, 0);
    cur = (cur == 2) ? 0 : cur + 1;
  }

#pragma unroll
  for (int mt = 0; mt < 4; ++mt)
#pragma unroll
    for (int nt = 0; nt < 2; ++nt)
#pragma unroll
      for (int r = 0; r < 4; ++r) {
        int row = byy * 128 + wm + mt * 16 + quad * 4 + r;
        int col = bxx * 64 + wn + nt * 16 + l16;
        out[(size_t)row * N + col] = acc[mt][nt][r];
      }
}

// ---------------- flash attention: r4-proven body, ONE q-tile per block ----------------
// r11 change (scheduling only; per-iter body/softmax/masking/output byte-identical
// to the thrice-refcheck-passed r4 kernel): drop the 2-pass {31-p, p} pairing ->
// grid (bh=64, 32), qt = 31 - blockIdx.y (LPT: longest blocks dispatched first).
// Mechanism: attn is dependency-chain bound (r10 counters: VALU 37.5% > Mfma 27.4%,
// occupancy 22%, neither pipe saturated). 32 KB LDS allows 5 resident blocks/CU but
// the 1024-block grid supplied exactly 4/CU; 2048 blocks keeps 5 resident
// (launch_bounds(256,5); 68 VGPR unaffected) -> +25% independent contexts to
// overlap the serial QK->exp2->PV chain. XCD locality preserved: linear block id
// % 8 depends only on bh & 7, so all q-tiles of a head stay on one XCD.
__global__ __launch_bounds__(256, 5) void attn_kernel(const __bf16* __restrict__ qb,
                                                      const __bf16* __restrict__ kb,
                                                      const __bf16* __restrict__ vtb,
                                                      __bf16* __restrict__ y) {
  // [buf][ K tile 64x64 (4096) | V^T tile 64x64 (4096) ] = 32 KB total
  __shared__ __bf16 kv_lds[2][8192];
  const int tid = threadIdx.x;
  const int lane = tid & 63;
  const int w = tid >> 6;
  const int l16 = lane & 15, quad = lane >> 4;
  const int bh = blockIdx.x;
  const int qt = 31 - blockIdx.y;  // 64-row q-tile index, longest-first (LPT)
  const int b = bh >> 4, h = bh & 15;
  const __bf16* kbase = kb + (size_t)bh * SS * DD;
  const __bf16* vtbase = vtb + (size_t)bh * DD * SS;

  // ---- hoisted LDS read offsets (element units; identical to proven kernel) ----
  const int e = l16 & 7;
  const int koff0 = l16 * 64 + ((quad ^ e) * 8);        // K frag, d 0..31 chunk
  const int koff1 = l16 * 64 + (((quad + 4) ^ e) * 8);  // K frag, d 32..63 chunk
  int voff[4];
#pragma unroll
  for (int kf = 0; kf < 4; ++kf)
    voff[kf] = 4096 + l16 * 64 + (((kf * 2 + (quad >> 1)) ^ e) * 8) + ((quad & 1) * 4);

  // ---- hoisted staging offsets ----
  int gK[2], gV[2], lK[2], lV[2];
#pragma unroll
  for (int i = 0; i < 2; ++i) {
    int L = tid + i * 256;
    int row = L >> 3, c = L & 7;
    gK[i] = row * DD + ((c ^ (row & 7)) * 8);
    lK[i] = L * 8;
    gV[i] = row * SS + ((c ^ (row & 7)) * 8);
    lV[i] = 4096 + L * 8;
  }
  auto stage = [&](int j, __bf16* buf) {
    const __bf16* kj = kbase + j * (64 * DD);
    const __bf16* vj = vtbase + j * 64;
#pragma unroll
    for (int i = 0; i < 2; ++i) async16(kj + gK[i], buf + lK[i]);
#pragma unroll
    for (int i = 0; i < 2; ++i) async16(vj + gV[i], buf + lV[i]);
  };

  // Q frags: lane holds Q[q = qt*64 + w*16 + l16][d = ks*32 + quad*8 + j]
  b16v8 qf[2];
#pragma unroll
  for (int ks = 0; ks < 2; ++ks)
    qf[ks] = *(const b16v8*)(qb + ((size_t)bh * SS + qt * 64 + w * 16 + l16) * DD + ks * 32 + quad * 8);

  f32x4 o[4];  // O^T[d = dt*16+quad*4+r][q = l16]
#pragma unroll
  for (int dt = 0; dt < 4; ++dt) o[dt] = f32x4{0.f, 0.f, 0.f, 0.f};
  f32x4 lv = {0.f, 0.f, 0.f, 0.f};  // deferred per-lane l partial sums

  stage(0, kv_lds[0]);  // prologue DMA

  for (int j = 0; j <= qt; ++j) {
    __syncthreads();  // drains vmcnt: tile j ready; buf[(j+1)&1] readers (iter j-1) done
    if (j < qt) stage(j + 1, kv_lds[(j + 1) & 1]);  // DMA covered by compute(j)
    const __bf16* buf = kv_lds[0] + ((j & 1) << 13);

    // S^T = K . Q^T - CMAX   (s[kf]: key = kf*16+quad*4+r, q = l16)
    f32x4 s[4];
#pragma unroll
    for (int kf = 0; kf < 4; ++kf) s[kf] = f32x4{-CMAX, -CMAX, -CMAX, -CMAX};
    __builtin_amdgcn_s_setprio(1);
#pragma unroll
    for (int kf = 0; kf < 4; ++kf) {
      b16v8 k0 = *(const b16v8*)(buf + koff0 + kf * 1024);
      b16v8 k1 = *(const b16v8*)(buf + koff1 + kf * 1024);
      s[kf] = __builtin_amdgcn_mfma_f32_16x16x32_bf16(k0, qf[0], s[kf], 0, 0, 0);
      s[kf] = __builtin_amdgcn_mfma_f32_16x16x32_bf16(k1, qf[1], s[kf], 0, 0, 0);
    }
    __builtin_amdgcn_s_setprio(0);
    // causal mask: only the diagonal 64-key tile (key_local > w*16 + l16)
    if (j == qt) {
      int ql = w * 16 + l16;
#pragma unroll
      for (int kf = 0; kf < 4; ++kf)
#pragma unroll
        for (int r = 0; r < 4; ++r)
          if (kf * 16 + quad * 4 + r > ql) s[kf][r] = -1e30f;
    }
    // P = exp2(S) (static max, no reduction, no rescale)
#pragma unroll
    for (int kf = 0; kf < 4; ++kf)
#pragma unroll
      for (int r = 0; r < 4; ++r) s[kf][r] = __builtin_amdgcn_exp2f(s[kf][r]);
    lv += (s[0] + s[1]) + (s[2] + s[3]);  // vector pk adds
    // O^T += V^T . P^T  (P^T already in B-operand layout of 16x16x16)
    __builtin_amdgcn_s_setprio(1);
#pragma unroll
    for (int kf = 0; kf < 4; ++kf) {
      b16v4 pf = {(__bf16)s[kf][0], (__bf16)s[kf][1], (__bf16)s[kf][2], (__bf16)s[kf][3]};
#pragma unroll
      for (int dt = 0; dt < 4; ++dt) {
        b16v4 vf = *(const b16v4*)(buf + voff[kf] + dt * 1024);
        o[dt] = mfma16x16x16_bf16(vf, pf, o[dt]);
      }
    }
    __builtin_amdgcn_s_setprio(0);
  }

  // final l: in-lane horizontal + cross-quad reduction
  float lr = (lv[0] + lv[1]) + (lv[2] + lv[3]);
  lr += __shfl_xor(lr, 16);
  lr += __shfl_xor(lr, 32);
  float inv = 1.0f / lr;
  int q = qt * 64 + w * 16 + l16;
#pragma unroll
  for (int dt = 0; dt < 4; ++dt) {
    b16v4 ov = {(__bf16)(o[dt][0] * inv), (__bf16)(o[dt][1] * inv),
                (__bf16)(o[dt][2] * inv), (__bf16)(o[dt][3] * inv)};
    *(b16v4*)(y + ((size_t)b * SS + q) * EE + h * 64 + dt * 16 + quad * 4) = ov;
  }
}

extern "C" void kernel_launch(void* const* d_in, const int* in_sizes, int n_in,
                              void* d_out, int out_size, void* d_ws, size_t ws_size,
                              hipStream_t stream) {
  (void)in_sizes; (void)n_in; (void)out_size; (void)ws_size;
  const float* x = (const float*)d_in[0];
  const float* w_att = (const float*)d_in[1];
  const float* w_proj = (const float*)d_in[2];
  float* out = (float*)d_out;

  char* ws = (char*)d_ws;
  size_t off = 0;
  auto alloc = [&](size_t elems) { __bf16* p = (__bf16*)(ws + off); off += elems * 2; return p; };
  __bf16* xb = alloc(8388608);     // x bf16; reused as y after attention
  __bf16* qb = alloc(8388608);     // [BH][S][D] (pre-scaled by 0.125*log2e)
  __bf16* kb = alloc(8388608);     // [BH][S][D]
  __bf16* vtb = alloc(8388608);    // [BH][D][S] (written transposed by gemm_qkv)
  __bf16* watt = alloc(3145728);   // w_att^T  [3072][1024]
  __bf16* wproj = alloc(1048576);  // w_proj^T [1024][1024]

  prep_kernel<<<12288, 256, 0, stream>>>(x, xb, w_att, watt, w_proj, wproj);
  gemm_qkv<<<dim3(24, 64), 256, 0, stream>>>(xb, watt, qb, kb, vtb, 1024);
  attn_kernel<<<dim3(64, 32), 256, 0, stream>>>(qb, kb, vtb, xb);
  gemm_proj<<<dim3(16, 64), 256, 0, stream>>>(xb, wproj, out, 1024, 1024);
}

// Round 12
// 235.743 us; speedup vs baseline: 1.0716x; 1.0176x over previous
//
#include <hip/hip_runtime.h>
#include <hip/hip_bf16.h>

typedef __bf16 b16v8 __attribute__((ext_vector_type(8)));
typedef __bf16 b16v4 __attribute__((ext_vector_type(4)));
typedef float  f32x4 __attribute__((ext_vector_type(4)));

#define BB 4
#define SS 2048
#define EE 1024
#define HH 16
#define DD 64

// 0.125 * log2(e): folds softmax scale + exp->exp2 conversion into q.
#define QSCALE 0.18033688011112042f
// Static softmax "max" in log2 domain: |s| <= ~10 even at 6 sigma, so
// exp2(s - 20) is in [2^-50, 2^-11] -- no overflow, no relative-precision loss.
#define CMAX 20.0f

__device__ __forceinline__ void async16(const __bf16* g, __bf16* l) {
  typedef __attribute__((address_space(1))) const unsigned int gu32;
  typedef __attribute__((address_space(3))) unsigned int lu32;
  __builtin_amdgcn_global_load_lds((gu32*)g, (lu32*)l, 16, 0, 0);
}

__device__ __forceinline__ f32x4 mfma16x16x16_bf16(b16v4 a, b16v4 b, f32x4 c) {
#if __has_builtin(__builtin_amdgcn_mfma_f32_16x16x16_bf16)
  return __builtin_amdgcn_mfma_f32_16x16x16_bf16(a, b, c, 0, 0, 0);
#else
  typedef short s16v4 __attribute__((ext_vector_type(4)));
  union U { b16v4 h; s16v4 s; };
  U ua, ub; ua.h = a; ub.h = b;
  return __builtin_amdgcn_mfma_f32_16x16x16bf16_1k(ua.s, ub.s, c, 0, 0, 0);
#endif
}

// ---------- merged prep: cast x + transpose both weights (one launch) ----------
__global__ __launch_bounds__(256) void prep_kernel(const float* __restrict__ x,
                                                   __bf16* __restrict__ xb,
                                                   const float* __restrict__ w_att,
                                                   __bf16* __restrict__ watt,
                                                   const float* __restrict__ w_proj,
                                                   __bf16* __restrict__ wproj) {
  __shared__ float t[32][33];
  const int bid = blockIdx.x;
  if (bid < 8192) {
    int i = bid * 256 + threadIdx.x;
    float4 f = ((const float4*)x)[i];
    b16v4 o = {(__bf16)f.x, (__bf16)f.y, (__bf16)f.z, (__bf16)f.w};
    ((b16v4*)xb)[i] = o;
    return;
  }
  const float* w;
  __bf16* wt;
  int N, local;
  if (bid < 11264) { w = w_att; wt = watt; N = 3072; local = bid - 8192; }
  else             { w = w_proj; wt = wproj; N = 1024; local = bid - 11264; }
  const int K = 1024;
  int n0 = (local % (N >> 5)) * 32, k0 = (local / (N >> 5)) * 32;
  int tx = threadIdx.x & 31, ty = threadIdx.x >> 5;  // 32x8
#pragma unroll
  for (int j = 0; j < 32; j += 8)
    t[ty + j][tx] = w[(size_t)(k0 + ty + j) * N + n0 + tx];
  __syncthreads();
#pragma unroll
  for (int j = 0; j < 32; j += 8)
    wt[(size_t)(n0 + ty + j) * K + k0 + tx] = (__bf16)t[tx][ty + j];
}

// ---------------- QKV GEMM: exact r7 kernel (best-measured, refcheck-passed) ----------------
// 128x128 tile, BK=32, 3-buffer global_load_lds staging with counted vmcnt(4)
// (retires the stage issued TWO bodies ago), raw s_barrier, XOR chunk swizzle,
// XCD-bijective block swizzle. 73.8 us measured.
__global__ __launch_bounds__(256) void gemm_qkv(const __bf16* __restrict__ A,
                                                const __bf16* __restrict__ Bt,
                                                __bf16* __restrict__ qb,
                                                __bf16* __restrict__ kb,
                                                __bf16* __restrict__ vtb,
                                                int K) {
  __shared__ __bf16 a_lds[3][128 * 32];
  __shared__ __bf16 b_lds[3][128 * 32];
  const int tid = threadIdx.x;
  const int lane = tid & 63;
  const int w = tid >> 6;
  const int wm = (w >> 1) * 64, wn = (w & 1) * 64;
  const int l16 = lane & 15, quad = lane >> 4;

  const int gx = gridDim.x;
  const int nwg = gx * gridDim.y;
  const int bid0 = blockIdx.y * gx + blockIdx.x;
  const int qq = nwg >> 3;
  const int xcd = bid0 & 7, idx = bid0 >> 3;
  const int wgid = xcd * qq + idx;
  const int bxx = wgid % gx, byy = wgid / gx;

  const __bf16* Ab = A + (size_t)byy * 128 * K;
  const __bf16* Bb = Bt + (size_t)bxx * 128 * K;

  auto stage = [&](int k0, int bufi) {
#pragma unroll
    for (int i = 0; i < 2; ++i) {
      int c = tid + i * 256;
      int row = c >> 2, ch = c & 3;
      async16(Ab + (size_t)row * K + k0 + ((ch ^ (row & 3)) * 8), a_lds[bufi] + c * 8);
    }
#pragma unroll
    for (int i = 0; i < 2; ++i) {
      int c = tid + i * 256;
      int row = c >> 2, ch = c & 3;
      async16(Bb + (size_t)row * K + k0 + ((ch ^ (row & 3)) * 8), b_lds[bufi] + c * 8);
    }
  };

  f32x4 acc[4][4];
#pragma unroll
  for (int i = 0; i < 4; ++i)
#pragma unroll
    for (int j = 0; j < 4; ++j) acc[i][j] = f32x4{0.f, 0.f, 0.f, 0.f};

  stage(0, 0);
  stage(32, 1);
  const int KT = K >> 5;
  const int sw = (quad ^ (l16 & 3)) * 8;
  int cur = 0;
  for (int kt = 0; kt < KT; ++kt) {
    if (kt + 1 < KT) asm volatile("s_waitcnt vmcnt(4)" ::: "memory");
    else             asm volatile("s_waitcnt vmcnt(0)" ::: "memory");
    __builtin_amdgcn_s_barrier();
    if (kt + 2 < KT) {
      int stb = cur + 2; if (stb > 2) stb -= 3;
      stage((kt + 2) << 5, stb);
    }
    const __bf16* ab = a_lds[cur];
    const __bf16* bb = b_lds[cur];
    b16v8 af[4], bf4[4];
#pragma unroll
    for (int t = 0; t < 4; ++t) {
      af[t] = *(const b16v8*)(ab + (wm + t * 16 + l16) * 32 + sw);
      bf4[t] = *(const b16v8*)(bb + (wn + t * 16 + l16) * 32 + sw);
    }
#pragma unroll
    for (int mt = 0; mt < 4; ++mt)
#pragma unroll
      for (int nt = 0; nt < 4; ++nt)
        acc[mt][nt] = __builtin_amdgcn_mfma_f32_16x16x32_bf16(af[mt], bf4[nt], acc[mt][nt], 0, 0, 0);
    cur = (cur == 2) ? 0 : cur + 1;
  }

#pragma unroll
  for (int mt = 0; mt < 4; ++mt)
#pragma unroll
    for (int nt = 0; nt < 4; ++nt) {
      int row = byy * 128 + wm + mt * 16 + quad * 4;
      int col = bxx * 128 + wn + nt * 16 + l16;
      int b = row >> 11, s = row & 2047;
      int sec = col >> 10, cc = col & 1023;
      int h = cc >> 6, d = cc & 63;
      if (sec == 2) {
        b16v4 vv = {(__bf16)acc[mt][nt][0], (__bf16)acc[mt][nt][1],
                    (__bf16)acc[mt][nt][2], (__bf16)acc[mt][nt][3]};
        *(b16v4*)(vtb + ((size_t)(b * HH + h) * DD + d) * SS + s) = vv;
      } else {
        __bf16* dst = (sec == 0) ? qb : kb;
        float sc = (sec == 0) ? QSCALE : 1.0f;
#pragma unroll
        for (int r = 0; r < 4; ++r)
          dst[(((size_t)(b * HH + h) * SS + s + r) << 6) + d] = (__bf16)(acc[mt][nt][r] * sc);
      }
    }
}

// ---------------- proj GEMM: exact r7 kernel ----------------
__global__ __launch_bounds__(256) void gemm_proj(const __bf16* __restrict__ A,
                                                 const __bf16* __restrict__ Bt,
                                                 float* __restrict__ out,
                                                 int N, int K) {
  __shared__ __bf16 a_lds[3][128 * 32];
  __shared__ __bf16 b_lds[3][64 * 32];
  const int tid = threadIdx.x;
  const int lane = tid & 63;
  const int w = tid >> 6;
  const int wm = (w >> 1) * 64, wn = (w & 1) * 32;
  const int l16 = lane & 15, quad = lane >> 4;

  const int gx = gridDim.x;
  const int nwg = gx * gridDim.y;
  const int bid0 = blockIdx.y * gx + blockIdx.x;
  const int qq = nwg >> 3;
  const int xcd = bid0 & 7, idx = bid0 >> 3;
  const int wgid = xcd * qq + idx;
  const int bxx = wgid % gx, byy = wgid / gx;

  const __bf16* Ab = A + (size_t)byy * 128 * K;
  const __bf16* Bb = Bt + (size_t)bxx * 64 * K;

  auto stage = [&](int k0, int bufi) {
#pragma unroll
    for (int i = 0; i < 2; ++i) {
      int c = tid + i * 256;
      int row = c >> 2, ch = c & 3;
      async16(Ab + (size_t)row * K + k0 + ((ch ^ (row & 3)) * 8), a_lds[bufi] + c * 8);
    }
    {
      int c = tid;
      int row = c >> 2, ch = c & 3;
      async16(Bb + (size_t)row * K + k0 + ((ch ^ (row & 3)) * 8), b_lds[bufi] + c * 8);
    }
  };

  f32x4 acc[4][2];
#pragma unroll
  for (int i = 0; i < 4; ++i)
#pragma unroll
    for (int j = 0; j < 2; ++j) acc[i][j] = f32x4{0.f, 0.f, 0.f, 0.f};

  stage(0, 0);
  stage(32, 1);
  const int KT = K >> 5;
  const int sw = (quad ^ (l16 & 3)) * 8;
  int cur = 0;
  for (int kt = 0; kt < KT; ++kt) {
    if (kt + 1 < KT) asm volatile("s_waitcnt vmcnt(3)" ::: "memory");
    else             asm volatile("s_waitcnt vmcnt(0)" ::: "memory");
    __builtin_amdgcn_s_barrier();
    if (kt + 2 < KT) {
      int stb = cur + 2; if (stb > 2) stb -= 3;
      stage((kt + 2) << 5, stb);
    }
    const __bf16* ab = a_lds[cur];
    const __bf16* bb = b_lds[cur];
    b16v8 af[4], bf4[2];
#pragma unroll
    for (int t = 0; t < 4; ++t)
      af[t] = *(const b16v8*)(ab + (wm + t * 16 + l16) * 32 + sw);
#pragma unroll
    for (int t = 0; t < 2; ++t)
      bf4[t] = *(const b16v8*)(bb + (wn + t * 16 + l16) * 32 + sw);
#pragma unroll
    for (int mt = 0; mt < 4; ++mt)
#pragma unroll
      for (int nt = 0; nt < 2; ++nt)
        acc[mt][nt] = __builtin_amdgcn_mfma_f32_16x16x32_bf16(af[mt], bf4[nt], acc[mt][nt], 0, 0, 0);
    cur = (cur == 2) ? 0 : cur + 1;
  }

#pragma unroll
  for (int mt = 0; mt < 4; ++mt)
#pragma unroll
    for (int nt = 0; nt < 2; ++nt)
#pragma unroll
      for (int r = 0; r < 4; ++r) {
        int row = byy * 128 + wm + mt * 16 + quad * 4 + r;
        int col = bxx * 64 + wn + nt * 16 + l16;
        out[(size_t)row * N + col] = acc[mt][nt][r];
      }
}

// ---------------- flash attention: exact r4/r7 kernel (refcheck-passed 3x) ----------------
// Grid (bh=64, p=16): bh on blockIdx.x so all p-blocks of a bh share an XCD (id%8).
// Block p handles 64-row q-tiles {31-p, p} -> uniform 33 j-iters of 64 keys.
// S^T = K.Q^T (16x16x32, operand swap); P^T register layout == B-operand of
// 16x16x16 => PV with zero data movement. Static-max exp2 softmax, l-sum deferred.
// 32 KB LDS -> 4 blk/CU. T5 s_setprio(1) around MFMA clusters.
__global__ __launch_bounds__(256, 4) void attn_kernel(const __bf16* __restrict__ qb,
                                                      const __bf16* __restrict__ kb,
                                                      const __bf16* __restrict__ vtb,
                                                      __bf16* __restrict__ y) {
  __shared__ __bf16 kv_lds[2][8192];
  const int tid = threadIdx.x;
  const int lane = tid & 63;
  const int w = tid >> 6;
  const int l16 = lane & 15, quad = lane >> 4;
  const int bh = blockIdx.x, p = blockIdx.y;
  const int b = bh >> 4, h = bh & 15;
  const __bf16* kbase = kb + (size_t)bh * SS * DD;
  const __bf16* vtbase = vtb + (size_t)bh * DD * SS;

  const int e = l16 & 7;
  const int koff0 = l16 * 64 + ((quad ^ e) * 8);
  const int koff1 = l16 * 64 + (((quad + 4) ^ e) * 8);
  int voff[4];
#pragma unroll
  for (int kf = 0; kf < 4; ++kf)
    voff[kf] = 4096 + l16 * 64 + (((kf * 2 + (quad >> 1)) ^ e) * 8) + ((quad & 1) * 4);

  int gK[2], gV[2], lK[2], lV[2];
#pragma unroll
  for (int i = 0; i < 2; ++i) {
    int L = tid + i * 256;
    int row = L >> 3, c = L & 7;
    gK[i] = row * DD + ((c ^ (row & 7)) * 8);
    lK[i] = L * 8;
    gV[i] = row * SS + ((c ^ (row & 7)) * 8);
    lV[i] = 4096 + L * 8;
  }
  auto stage = [&](int j, __bf16* buf) {
    const __bf16* kj = kbase + j * (64 * DD);
    const __bf16* vj = vtbase + j * 64;
#pragma unroll
    for (int i = 0; i < 2; ++i) async16(kj + gK[i], buf + lK[i]);
#pragma unroll
    for (int i = 0; i < 2; ++i) async16(vj + gV[i], buf + lV[i]);
  };

#pragma unroll
  for (int t = 0; t < 2; ++t) {
    const int qt = (t == 0) ? (31 - p) : p;

    b16v8 qf[2];
#pragma unroll
    for (int ks = 0; ks < 2; ++ks)
      qf[ks] = *(const b16v8*)(qb + ((size_t)bh * SS + qt * 64 + w * 16 + l16) * DD + ks * 32 + quad * 8);

    f32x4 o[4];
#pragma unroll
    for (int dt = 0; dt < 4; ++dt) o[dt] = f32x4{0.f, 0.f, 0.f, 0.f};
    f32x4 lv = {0.f, 0.f, 0.f, 0.f};

    __syncthreads();
    stage(0, kv_lds[0]);

    for (int j = 0; j <= qt; ++j) {
      __syncthreads();
      if (j < qt) stage(j + 1, kv_lds[(j + 1) & 1]);
      const __bf16* buf = kv_lds[0] + ((j & 1) << 13);

      f32x4 s[4];
#pragma unroll
      for (int kf = 0; kf < 4; ++kf) s[kf] = f32x4{-CMAX, -CMAX, -CMAX, -CMAX};
      __builtin_amdgcn_s_setprio(1);
#pragma unroll
      for (int kf = 0; kf < 4; ++kf) {
        b16v8 k0 = *(const b16v8*)(buf + koff0 + kf * 1024);
        b16v8 k1 = *(const b16v8*)(buf + koff1 + kf * 1024);
        s[kf] = __builtin_amdgcn_mfma_f32_16x16x32_bf16(k0, qf[0], s[kf], 0, 0, 0);
        s[kf] = __builtin_amdgcn_mfma_f32_16x16x32_bf16(k1, qf[1], s[kf], 0, 0, 0);
      }
      __builtin_amdgcn_s_setprio(0);
      if (j == qt) {
        int ql = w * 16 + l16;
#pragma unroll
        for (int kf = 0; kf < 4; ++kf)
#pragma unroll
          for (int r = 0; r < 4; ++r)
            if (kf * 16 + quad * 4 + r > ql) s[kf][r] = -1e30f;
      }
#pragma unroll
      for (int kf = 0; kf < 4; ++kf)
#pragma unroll
        for (int r = 0; r < 4; ++r) s[kf][r] = __builtin_amdgcn_exp2f(s[kf][r]);
      lv += (s[0] + s[1]) + (s[2] + s[3]);
      __builtin_amdgcn_s_setprio(1);
#pragma unroll
      for (int kf = 0; kf < 4; ++kf) {
        b16v4 pf = {(__bf16)s[kf][0], (__bf16)s[kf][1], (__bf16)s[kf][2], (__bf16)s[kf][3]};
#pragma unroll
        for (int dt = 0; dt < 4; ++dt) {
          b16v4 vf = *(const b16v4*)(buf + voff[kf] + dt * 1024);
          o[dt] = mfma16x16x16_bf16(vf, pf, o[dt]);
        }
      }
      __builtin_amdgcn_s_setprio(0);
    }

    float lr = (lv[0] + lv[1]) + (lv[2] + lv[3]);
    lr += __shfl_xor(lr, 16);
    lr += __shfl_xor(lr, 32);
    float inv = 1.0f / lr;
    int q = qt * 64 + w * 16 + l16;
#pragma unroll
    for (int dt = 0; dt < 4; ++dt) {
      b16v4 ov = {(__bf16)(o[dt][0] * inv), (__bf16)(o[dt][1] * inv),
                  (__bf16)(o[dt][2] * inv), (__bf16)(o[dt][3] * inv)};
      *(b16v4*)(y + ((size_t)b * SS + q) * EE + h * 64 + dt * 16 + quad * 4) = ov;
    }
  }
}

extern "C" void kernel_launch(void* const* d_in, const int* in_sizes, int n_in,
                              void* d_out, int out_size, void* d_ws, size_t ws_size,
                              hipStream_t stream) {
  (void)in_sizes; (void)n_in; (void)out_size; (void)ws_size;
  const float* x = (const float*)d_in[0];
  const float* w_att = (const float*)d_in[1];
  const float* w_proj = (const float*)d_in[2];
  float* out = (float*)d_out;

  char* ws = (char*)d_ws;
  size_t off = 0;
  auto alloc = [&](size_t elems) { __bf16* p = (__bf16*)(ws + off); off += elems * 2; return p; };
  __bf16* xb = alloc(8388608);     // x bf16; reused as y after attention
  __bf16* qb = alloc(8388608);     // [BH][S][D] (pre-scaled by 0.125*log2e)
  __bf16* kb = alloc(8388608);     // [BH][S][D]
  __bf16* vtb = alloc(8388608);    // [BH][D][S] (written transposed by gemm_qkv)
  __bf16* watt = alloc(3145728);   // w_att^T  [3072][1024]
  __bf16* wproj = alloc(1048576);  // w_proj^T [1024][1024]

  prep_kernel<<<12288, 256, 0, stream>>>(x, xb, w_att, watt, w_proj, wproj);
  gemm_qkv<<<dim3(24, 64), 256, 0, stream>>>(xb, watt, qb, kb, vtb, 1024);
  attn_kernel<<<dim3(64, 16), 256, 0, stream>>>(qb, kb, vtb, xb);
  gemm_proj<<<dim3(16, 64), 256, 0, stream>>>(xb, wproj, out, 1024, 1024);
}